// Round 1
// baseline (2039.005 us; speedup 1.0000x reference)
//
#include <hip/hip_runtime.h>
#include <math.h>

#define BB 16
#define INC 1024
#define PP 256
#define NHEADS 4
#define DD 64
#define NN 1024

__device__ __forceinline__ float gelu_exact(float v) {
    return 0.5f * v * (1.0f + erff(v * 0.70710678118654752440f));
}

// dst[k*M + m] = src[m*K + k]   (src is [M,K] row-major)
__global__ void transpose_k(const float* __restrict__ src, float* __restrict__ dst,
                            int M, int K) {
    int idx = blockIdx.x * 256 + threadIdx.x;
    if (idx < M * K) {
        int m = idx / K;
        int k = idx - m * K;
        dst[k * M + m] = src[idx];
    }
}

// C[b][m][n] = sum_k At[k][m] * Bm[b][k][n] (+bias[m])
// mode 0: plain (+bias if non-null). mode 2: gelu(acc) + resid[b][m][n].
__global__ __launch_bounds__(256) void gemm_k(
    const float* __restrict__ At, const float* __restrict__ Bm,
    const float* __restrict__ bias, const float* __restrict__ resid,
    float* __restrict__ C, int M, int N, int K, int mode)
{
    __shared__ float As[16][64];
    __shared__ float Bs[16][64];
    int tid = threadIdx.x;
    int ti = tid >> 4, tj = tid & 15;
    int m0 = blockIdx.y * 64, n0 = blockIdx.x * 64;
    long b = blockIdx.z;
    const float* Bp = Bm + b * (long)K * N;
    int lm = tid & 63, lk = tid >> 6;

    float acc[4][4] = {};

    for (int k0 = 0; k0 < K; k0 += 16) {
        #pragma unroll
        for (int r = 0; r < 4; ++r) {
            int kk = lk + r * 4;
            As[kk][lm] = At[(long)(k0 + kk) * M + m0 + lm];
            Bs[kk][lm] = Bp[(long)(k0 + kk) * N + n0 + lm];
        }
        __syncthreads();
        #pragma unroll
        for (int kk = 0; kk < 16; ++kk) {
            float4 a = *(const float4*)&As[kk][ti * 4];
            float4 bb = *(const float4*)&Bs[kk][tj * 4];
            acc[0][0] += a.x * bb.x; acc[0][1] += a.x * bb.y; acc[0][2] += a.x * bb.z; acc[0][3] += a.x * bb.w;
            acc[1][0] += a.y * bb.x; acc[1][1] += a.y * bb.y; acc[1][2] += a.y * bb.z; acc[1][3] += a.y * bb.w;
            acc[2][0] += a.z * bb.x; acc[2][1] += a.z * bb.y; acc[2][2] += a.z * bb.z; acc[2][3] += a.z * bb.w;
            acc[3][0] += a.w * bb.x; acc[3][1] += a.w * bb.y; acc[3][2] += a.w * bb.z; acc[3][3] += a.w * bb.w;
        }
        __syncthreads();
    }

    #pragma unroll
    for (int ii = 0; ii < 4; ++ii) {
        int m = m0 + ti * 4 + ii;
        float bv = bias ? bias[m] : 0.0f;
        long row = b * (long)M * N + (long)m * N + n0 + tj * 4;
        float4 r;
        r.x = acc[ii][0] + bv;
        r.y = acc[ii][1] + bv;
        r.z = acc[ii][2] + bv;
        r.w = acc[ii][3] + bv;
        if (mode == 2) {
            float4 xr = *(const float4*)&resid[row];
            r.x = gelu_exact(r.x) + xr.x;
            r.y = gelu_exact(r.y) + xr.y;
            r.z = gelu_exact(r.z) + xr.z;
            r.w = gelu_exact(r.w) + xr.w;
        }
        *(float4*)&C[row] = r;
    }
}

// Fused attention, flash-style. q/k/v: [B*H, D, N]. o: [B*H, D, N].
// S[i,j] = sum_d q[d,i]k[d,j] + sum_d pos[d,i]q[d,j]  (D_eff = 128)
__global__ __launch_bounds__(256) void attn_k(
    const float* __restrict__ q, const float* __restrict__ k, const float* __restrict__ v,
    const float* __restrict__ rel_h, const float* __restrict__ rel_w,
    float* __restrict__ o)
{
    __shared__ float Qp[32][64];
    __shared__ float Kp[32][64];
    __shared__ float Vs[64][68];
    __shared__ float Ps[64][68];
    __shared__ float part[64][17];
    __shared__ float sm_m[64], sm_al[64], sm_l[64];

    int tid = threadIdx.x;
    int ti = tid >> 4, tj = tid & 15;
    int i0 = blockIdx.x * 64;
    int h = blockIdx.y;
    int b = blockIdx.z;
    long base = (long)(b * NHEADS + h) * DD * NN;
    const float* qb = q + base;
    const float* kb = k + base;
    const float* vb = v + base;
    const float* rh = rel_h + h * DD * 32;  // [d][hh]
    const float* rw = rel_w + h * DD * 32;  // [d][w]
    int lm = tid & 63, lk = tid >> 6;

    float acc_o[4][4] = {};
    if (tid < 64) { sm_m[tid] = -1e30f; sm_l[tid] = 0.0f; }

    for (int j0 = 0; j0 < NN; j0 += 64) {
        float s[4][4] = {};
        for (int kt = 0; kt < 4; ++kt) {
            __syncthreads();
            #pragma unroll
            for (int r = 0; r < 8; ++r) {
                int c = lk + r * 4;            // 0..31
                int kc = kt * 32 + c;          // 0..127
                float qv, kv;
                if (kc < 64) {
                    qv = qb[(long)kc * NN + i0 + lm];
                    kv = kb[(long)kc * NN + j0 + lm];
                } else {
                    int d = kc - 64;
                    int ig = i0 + lm;
                    qv = rh[d * 32 + (ig & 31)] + rw[d * 32 + (ig >> 5)];
                    kv = qb[(long)d * NN + j0 + lm];
                }
                Qp[c][lm] = qv;
                Kp[c][lm] = kv;
            }
            if (kt == 0) {
                #pragma unroll
                for (int r = 0; r < 16; ++r) {
                    int d = lk + r * 4;
                    Vs[d][lm] = vb[(long)d * NN + j0 + lm];
                }
            }
            __syncthreads();
            #pragma unroll
            for (int c = 0; c < 32; ++c) {
                float4 a = *(const float4*)&Qp[c][ti * 4];
                float4 bb = *(const float4*)&Kp[c][tj * 4];
                s[0][0] += a.x * bb.x; s[0][1] += a.x * bb.y; s[0][2] += a.x * bb.z; s[0][3] += a.x * bb.w;
                s[1][0] += a.y * bb.x; s[1][1] += a.y * bb.y; s[1][2] += a.y * bb.z; s[1][3] += a.y * bb.w;
                s[2][0] += a.z * bb.x; s[2][1] += a.z * bb.y; s[2][2] += a.z * bb.z; s[2][3] += a.z * bb.w;
                s[3][0] += a.w * bb.x; s[3][1] += a.w * bb.y; s[3][2] += a.w * bb.z; s[3][3] += a.w * bb.w;
            }
        }
        // per-thread row maxes -> part
        #pragma unroll
        for (int ii = 0; ii < 4; ++ii) {
            float mx = fmaxf(fmaxf(s[ii][0], s[ii][1]), fmaxf(s[ii][2], s[ii][3]));
            part[ti * 4 + ii][tj] = mx;
        }
        __syncthreads();
        if (tid < 64) {
            float mx = part[tid][0];
            #pragma unroll
            for (int u = 1; u < 16; ++u) mx = fmaxf(mx, part[tid][u]);
            float m_old = sm_m[tid];
            float m_new = fmaxf(m_old, mx);
            sm_m[tid] = m_new;
            sm_al[tid] = __expf(m_old - m_new);
        }
        __syncthreads();
        #pragma unroll
        for (int ii = 0; ii < 4; ++ii) {
            int i = ti * 4 + ii;
            float al = sm_al[i];
            float mv = sm_m[i];
            #pragma unroll
            for (int jj = 0; jj < 4; ++jj) acc_o[ii][jj] *= al;
            float psum = 0.0f;
            #pragma unroll
            for (int jj = 0; jj < 4; ++jj) {
                float p = __expf(s[ii][jj] - mv);
                Ps[i][tj * 4 + jj] = p;
                psum += p;
            }
            part[i][tj] = psum;
        }
        __syncthreads();
        if (tid < 64) {
            float sum = 0.0f;
            #pragma unroll
            for (int u = 0; u < 16; ++u) sum += part[tid][u];
            sm_l[tid] = sm_l[tid] * sm_al[tid] + sum;
        }
        // PV: acc_o[ii][jj] += sum_j Ps[i][j] * Vs[d][j]
        #pragma unroll
        for (int js = 0; js < 16; ++js) {
            float4 pv[4], vv[4];
            #pragma unroll
            for (int ii = 0; ii < 4; ++ii) pv[ii] = *(const float4*)&Ps[ti * 4 + ii][js * 4];
            #pragma unroll
            for (int jj = 0; jj < 4; ++jj) vv[jj] = *(const float4*)&Vs[tj * 4 + jj][js * 4];
            #pragma unroll
            for (int ii = 0; ii < 4; ++ii)
                #pragma unroll
                for (int jj = 0; jj < 4; ++jj)
                    acc_o[ii][jj] += pv[ii].x * vv[jj].x + pv[ii].y * vv[jj].y
                                   + pv[ii].z * vv[jj].z + pv[ii].w * vv[jj].w;
        }
    }
    __syncthreads();
    #pragma unroll
    for (int ii = 0; ii < 4; ++ii) {
        int i = ti * 4 + ii;
        float inv = 1.0f / sm_l[i];
        #pragma unroll
        for (int jj = 0; jj < 4; ++jj) {
            int d = tj * 4 + jj;
            o[base + (long)d * NN + i0 + i] = acc_o[ii][jj] * inv;
        }
    }
}

// In-place LayerNorm over P=256 channels at each (b, n). o: [B, P, N].
__global__ __launch_bounds__(256) void ln_k(float* __restrict__ o,
                                            const float* __restrict__ lw,
                                            const float* __restrict__ lb)
{
    __shared__ float T[256][32];
    __shared__ float ps[8][32];
    __shared__ float pq[8][32];
    __shared__ float smean[32], srstd[32];
    int tid = threadIdx.x;
    int b = blockIdx.y;
    int n0 = blockIdx.x * 32;
    long base = (long)b * PP * NN;
    int c = tid & 31, g = tid >> 5;  // g: 0..7

    #pragma unroll
    for (int r = 0; r < 32; ++r) {
        int p = g + r * 8;
        T[p][c] = o[base + (long)p * NN + n0 + c];
    }
    __syncthreads();
    float sum = 0.0f, sq = 0.0f;
    #pragma unroll
    for (int r = 0; r < 32; ++r) {
        float x = T[g * 32 + r][c];
        sum += x; sq += x * x;
    }
    ps[g][c] = sum; pq[g][c] = sq;
    __syncthreads();
    if (tid < 32) {
        float s = 0.0f, q2 = 0.0f;
        #pragma unroll
        for (int g2 = 0; g2 < 8; ++g2) { s += ps[g2][tid]; q2 += pq[g2][tid]; }
        float mean = s * (1.0f / 256.0f);
        float var = q2 * (1.0f / 256.0f) - mean * mean;
        smean[tid] = mean;
        srstd[tid] = rsqrtf(var + 1e-6f);
    }
    __syncthreads();
    #pragma unroll
    for (int r = 0; r < 32; ++r) {
        int p = g * 32 + r;
        float x = T[p][c];
        float y = (x - smean[c]) * srstd[c] * lw[p] + lb[p];
        o[base + (long)p * NN + n0 + c] = y;
    }
}

extern "C" void kernel_launch(void* const* d_in, const int* in_sizes, int n_in,
                              void* d_out, int out_size, void* d_ws, size_t ws_size,
                              hipStream_t stream) {
    const float* x     = (const float*)d_in[0];
    const float* w_ds  = (const float*)d_in[1];
    const float* wq    = (const float*)d_in[2];
    const float* bq    = (const float*)d_in[3];
    const float* wk    = (const float*)d_in[4];
    const float* bk    = (const float*)d_in[5];
    const float* wv    = (const float*)d_in[6];
    const float* bv    = (const float*)d_in[7];
    const float* rel_h = (const float*)d_in[8];
    const float* rel_w = (const float*)d_in[9];
    const float* ln_w  = (const float*)d_in[10];
    const float* ln_b  = (const float*)d_in[11];
    const float* w1    = (const float*)d_in[12];
    float* out = (float*)d_out;

    float* ws = (float*)d_ws;
    float* out0 = ws;                       // [B, P, N] -- also attention output
    float* qb   = ws + 4194304;             // [B, P, N]
    float* kb   = ws + 8388608;
    float* vb   = ws + 12582912;
    float* wdst = ws + 16777216;            // [INC, P]
    float* wqt  = wdst + 262144;            // [P, P]
    float* wkt  = wqt + 65536;
    float* wvt  = wkt + 65536;
    float* w1t  = wvt + 65536;              // [P, INC]

    transpose_k<<<(PP * INC + 255) / 256, 256, 0, stream>>>(w_ds, wdst, PP, INC);
    transpose_k<<<(PP * PP + 255) / 256, 256, 0, stream>>>(wq, wqt, PP, PP);
    transpose_k<<<(PP * PP + 255) / 256, 256, 0, stream>>>(wk, wkt, PP, PP);
    transpose_k<<<(PP * PP + 255) / 256, 256, 0, stream>>>(wv, wvt, PP, PP);
    transpose_k<<<(INC * PP + 255) / 256, 256, 0, stream>>>(w1, w1t, INC, PP);

    // out0 = w_ds * x
    gemm_k<<<dim3(16, 4, 16), 256, 0, stream>>>(wdst, x, nullptr, nullptr, out0, PP, NN, INC, 0);
    // q/k/v
    gemm_k<<<dim3(16, 4, 16), 256, 0, stream>>>(wqt, out0, bq, nullptr, qb, PP, NN, PP, 0);
    gemm_k<<<dim3(16, 4, 16), 256, 0, stream>>>(wkt, out0, bk, nullptr, kb, PP, NN, PP, 0);
    gemm_k<<<dim3(16, 4, 16), 256, 0, stream>>>(wvt, out0, bv, nullptr, vb, PP, NN, PP, 0);
    // attention -> out0 (reuse)
    attn_k<<<dim3(16, 4, 16), 256, 0, stream>>>(qb, kb, vb, rel_h, rel_w, out0);
    // layernorm in-place
    ln_k<<<dim3(32, 16), 256, 0, stream>>>(out0, ln_w, ln_b);
    // out = gelu(w1 * y) + x
    gemm_k<<<dim3(16, 16, 16), 256, 0, stream>>>(w1t, out0, nullptr, x, out, INC, NN, PP, 2);
}

// Round 3
// 667.490 us; speedup vs baseline: 3.0547x; 3.0547x over previous
//
#include <hip/hip_runtime.h>
#include <hip/hip_bf16.h>
#include <math.h>

#define BB 16
#define INC 1024
#define PP 256
#define NHEADS 4
#define DD 64
#define NN 1024

typedef _Float16 f16_t;
typedef __attribute__((ext_vector_type(8))) _Float16 f16x8;
typedef __attribute__((ext_vector_type(4))) _Float16 f16x4;
typedef __attribute__((ext_vector_type(4))) float f32x4;

__device__ __forceinline__ float gelu_exact(float v) {
    return 0.5f * v * (1.0f + erff(v * 0.70710678118654752440f));
}

// dst[k*M + m] = src[m*K + k]   (src is [M,K] row-major)
__global__ void transpose_k(const float* __restrict__ src, float* __restrict__ dst,
                            int M, int K) {
    int idx = blockIdx.x * 256 + threadIdx.x;
    if (idx < M * K) {
        int m = idx / K;
        int k = idx - m * K;
        dst[k * M + m] = src[idx];
    }
}

// pos_t[h][i][d] = rel_h[h][d][i&31] + rel_w[h][d][i>>5]  (f16)
__global__ void pos_k(const float* __restrict__ rel_h, const float* __restrict__ rel_w,
                      f16_t* __restrict__ pos_t) {
    int idx = blockIdx.x * 256 + threadIdx.x;     // 4*1024*64
    int d = idx & 63;
    int i = (idx >> 6) & 1023;
    int h = idx >> 16;
    float v = rel_h[(h * 64 + d) * 32 + (i & 31)] + rel_w[(h * 64 + d) * 32 + (i >> 5)];
    pos_t[idx] = (f16_t)v;
}

// C[b][m][n] = sum_k At[k][m] * Bm[b][k][n] (+bias[m])
// mode 0: fp32 out (+bias). mode 1: f16 transposed out Cb[b][h][n][d] (+bias).
// mode 2: fp32 gelu(acc)+resid. mode 3: f16 native Cb[b][m][n] (+bias).
__global__ __launch_bounds__(256) void gemm_k(
    const float* __restrict__ At, const float* __restrict__ Bm,
    const float* __restrict__ bias, const float* __restrict__ resid,
    float* __restrict__ C, f16_t* __restrict__ Cb,
    int M, int N, int K, int mode)
{
    __shared__ float As[16][64];
    __shared__ float Bs[16][64];
    int tid = threadIdx.x;
    int ti = tid >> 4, tj = tid & 15;
    int m0 = blockIdx.y * 64, n0 = blockIdx.x * 64;
    long b = blockIdx.z;
    const float* Bp = Bm + b * (long)K * N;
    int lm = tid & 63, lk = tid >> 6;

    float acc[4][4] = {};

    for (int k0 = 0; k0 < K; k0 += 16) {
        #pragma unroll
        for (int r = 0; r < 4; ++r) {
            int kk = lk + r * 4;
            As[kk][lm] = At[(long)(k0 + kk) * M + m0 + lm];
            Bs[kk][lm] = Bp[(long)(k0 + kk) * N + n0 + lm];
        }
        __syncthreads();
        #pragma unroll
        for (int kk = 0; kk < 16; ++kk) {
            float4 a = *(const float4*)&As[kk][ti * 4];
            float4 bb = *(const float4*)&Bs[kk][tj * 4];
            acc[0][0] += a.x * bb.x; acc[0][1] += a.x * bb.y; acc[0][2] += a.x * bb.z; acc[0][3] += a.x * bb.w;
            acc[1][0] += a.y * bb.x; acc[1][1] += a.y * bb.y; acc[1][2] += a.y * bb.z; acc[1][3] += a.y * bb.w;
            acc[2][0] += a.z * bb.x; acc[2][1] += a.z * bb.y; acc[2][2] += a.z * bb.z; acc[2][3] += a.z * bb.w;
            acc[3][0] += a.w * bb.x; acc[3][1] += a.w * bb.y; acc[3][2] += a.w * bb.z; acc[3][3] += a.w * bb.w;
        }
        __syncthreads();
    }

    if (mode == 1) {
        // f16 transposed: Cb[b][h][n][d],  h = m0>>6, d = ti*4+ii, n = n0+tj*4+jj
        int h = m0 >> 6;
        float bvs[4];
        #pragma unroll
        for (int ii = 0; ii < 4; ++ii) bvs[ii] = bias[m0 + ti * 4 + ii];
        #pragma unroll
        for (int jj = 0; jj < 4; ++jj) {
            int n = n0 + tj * 4 + jj;
            f16x4 pk;
            #pragma unroll
            for (int ii = 0; ii < 4; ++ii) pk[ii] = (f16_t)(acc[ii][jj] + bvs[ii]);
            *(f16x4*)&Cb[(((long)b * 4 + h) * 1024 + n) * 64 + ti * 4] = pk;
        }
        return;
    }

    #pragma unroll
    for (int ii = 0; ii < 4; ++ii) {
        int m = m0 + ti * 4 + ii;
        float bv = bias ? bias[m] : 0.0f;
        long row = b * (long)M * N + (long)m * N + n0 + tj * 4;
        if (mode == 3) {
            f16x4 pk;
            #pragma unroll
            for (int jj = 0; jj < 4; ++jj) pk[jj] = (f16_t)(acc[ii][jj] + bv);
            *(f16x4*)&Cb[row] = pk;
            continue;
        }
        float4 r;
        r.x = acc[ii][0] + bv;
        r.y = acc[ii][1] + bv;
        r.z = acc[ii][2] + bv;
        r.w = acc[ii][3] + bv;
        if (mode == 2) {
            float4 xr = *(const float4*)&resid[row];
            r.x = gelu_exact(r.x) + xr.x;
            r.y = gelu_exact(r.y) + xr.y;
            r.z = gelu_exact(r.z) + xr.z;
            r.w = gelu_exact(r.w) + xr.w;
        }
        *(float4*)&C[row] = r;
    }
}

// MFMA flash attention (fp16 operands, fp32 accum).
// q_t,k_t: [B*H][N][64] f16 (n-major). v_b: [B*H][64][N] f16. pos_t: [H][N][64] f16.
// o: [B*H][64][N] fp32.
// S[i][j] = sum_{d<64} q[i][d]k[j][d] + sum_{d<64} pos[i][d]q[j][d]
__global__ __launch_bounds__(256) void attn_mfma(
    const f16_t* __restrict__ q_t, const f16_t* __restrict__ k_t,
    const f16_t* __restrict__ v_b, const f16_t* __restrict__ pos_t,
    float* __restrict__ o)
{
    __shared__ __align__(16) char plds[4][2048];  // per-wave P tile 16x64 f16, swizzled
    int tid = threadIdx.x;
    int wv = tid >> 6;
    int l = tid & 63;
    int lo = l & 15, hi = l >> 4;
    int h = blockIdx.y, b = blockIdx.z;
    int bh = b * 4 + h;
    int i_row = blockIdx.x * 64 + wv * 16;
    size_t qbase = (size_t)bh * 1024 * 64;

    // A fragments: lane row = lo, k = 8*hi + e  (per 32-wide k-step)
    f16x8 afr[4];
    {
        const f16_t* qr = q_t + qbase + (size_t)(i_row + lo) * 64 + hi * 8;
        afr[0] = *(const f16x8*)(qr);
        afr[1] = *(const f16x8*)(qr + 32);
        const f16_t* pr = pos_t + ((size_t)h * 1024 + i_row + lo) * 64 + hi * 8;
        afr[2] = *(const f16x8*)(pr);
        afr[3] = *(const f16x8*)(pr + 32);
    }

    f32x4 acc_o[4] = {};
    float m_run[4], l_run[4];
    #pragma unroll
    for (int r = 0; r < 4; ++r) { m_run[r] = -1e30f; l_run[r] = 0.0f; }

    char* pw = plds[wv];

    for (int j0 = 0; j0 < NN; j0 += 64) {
        f32x4 s[4] = {};
        #pragma unroll
        for (int ks = 0; ks < 4; ++ks) {
            const f16_t* kb = (ks < 2 ? k_t : q_t) + qbase + (size_t)(ks & 1) * 32 + hi * 8;
            #pragma unroll
            for (int f = 0; f < 4; ++f) {
                f16x8 bf = *(const f16x8*)(kb + (size_t)(j0 + f * 16 + lo) * 64);
                s[f] = __builtin_amdgcn_mfma_f32_16x16x32_f16(afr[ks], bf, s[f], 0, 0, 0);
            }
        }
        // online softmax: C/D layout row = hi*4+r, col = j0+16f+lo.
        float mnew[4];
        #pragma unroll
        for (int r = 0; r < 4; ++r) {
            float m = fmaxf(fmaxf(s[0][r], s[1][r]), fmaxf(s[2][r], s[3][r]));
            #pragma unroll
            for (int off = 1; off < 16; off <<= 1) m = fmaxf(m, __shfl_xor(m, off, 64));
            mnew[r] = fmaxf(m_run[r], m);
        }
        float rsum[4] = {0.f, 0.f, 0.f, 0.f};
        #pragma unroll
        for (int f = 0; f < 4; ++f) {
            #pragma unroll
            for (int r = 0; r < 4; ++r) {
                float p = __expf(s[f][r] - mnew[r]);
                s[f][r] = p;
                rsum[r] += p;
            }
        }
        #pragma unroll
        for (int r = 0; r < 4; ++r) {
            #pragma unroll
            for (int off = 1; off < 16; off <<= 1) rsum[r] += __shfl_xor(rsum[r], off, 64);
            float alpha = __expf(m_run[r] - mnew[r]);
            l_run[r] = l_run[r] * alpha + rsum[r];
            m_run[r] = mnew[r];
            #pragma unroll
            for (int f = 0; f < 4; ++f) acc_o[f][r] *= alpha;
        }
        // P -> LDS (f16, XOR-swizzled rows)
        #pragma unroll
        for (int f = 0; f < 4; ++f) {
            #pragma unroll
            for (int r = 0; r < 4; ++r) {
                int row = hi * 4 + r;
                int cb = (f * 16 + lo) * 2;
                *(f16_t*)(pw + row * 128 + (cb ^ ((row & 7) << 4))) = (f16_t)s[f][r];
            }
        }
        __syncthreads();
        // PV: A = P (lane row = lo), B = V^T (lane col d = 16f+lo, k = j-local)
        const f16_t* vb = v_b + qbase + (size_t)lo * 1024 + j0 + hi * 8;
        #pragma unroll
        for (int ks = 0; ks < 2; ++ks) {
            f16x8 pa = *(const f16x8*)(pw + lo * 128 + ((ks * 64 + hi * 16) ^ ((lo & 7) << 4)));
            #pragma unroll
            for (int f = 0; f < 4; ++f) {
                f16x8 vf = *(const f16x8*)(vb + (size_t)f * 16 * 1024 + ks * 32);
                acc_o[f] = __builtin_amdgcn_mfma_f32_16x16x32_f16(pa, vf, acc_o[f], 0, 0, 0);
            }
        }
        __syncthreads();
    }

    // store O[d][i] fp32: col d = 16f+lo, row i = i_row+hi*4+r
    #pragma unroll
    for (int r = 0; r < 4; ++r) {
        float inv = 1.0f / l_run[r];
        #pragma unroll
        for (int f = 0; f < 4; ++f) {
            o[qbase + (size_t)(f * 16 + lo) * 1024 + i_row + hi * 4 + r] = acc_o[f][r] * inv;
        }
    }
}

// In-place LayerNorm over P=256 channels at each (b, n). o: [B, P, N].
__global__ __launch_bounds__(256) void ln_k(float* __restrict__ o,
                                            const float* __restrict__ lw,
                                            const float* __restrict__ lb)
{
    __shared__ float T[256][32];
    __shared__ float ps[8][32];
    __shared__ float pq[8][32];
    __shared__ float smean[32], srstd[32];
    int tid = threadIdx.x;
    int b = blockIdx.y;
    int n0 = blockIdx.x * 32;
    long base = (long)b * PP * NN;
    int c = tid & 31, g = tid >> 5;

    #pragma unroll
    for (int r = 0; r < 32; ++r) {
        int p = g + r * 8;
        T[p][c] = o[base + (long)p * NN + n0 + c];
    }
    __syncthreads();
    float sum = 0.0f, sq = 0.0f;
    #pragma unroll
    for (int r = 0; r < 32; ++r) {
        float x = T[g * 32 + r][c];
        sum += x; sq += x * x;
    }
    ps[g][c] = sum; pq[g][c] = sq;
    __syncthreads();
    if (tid < 32) {
        float s = 0.0f, q2 = 0.0f;
        #pragma unroll
        for (int g2 = 0; g2 < 8; ++g2) { s += ps[g2][tid]; q2 += pq[g2][tid]; }
        float mean = s * (1.0f / 256.0f);
        float var = q2 * (1.0f / 256.0f) - mean * mean;
        smean[tid] = mean;
        srstd[tid] = rsqrtf(var + 1e-6f);
    }
    __syncthreads();
    #pragma unroll
    for (int r = 0; r < 32; ++r) {
        int p = g * 32 + r;
        float x = T[p][c];
        float y = (x - smean[c]) * srstd[c] * lw[p] + lb[p];
        o[base + (long)p * NN + n0 + c] = y;
    }
}

extern "C" void kernel_launch(void* const* d_in, const int* in_sizes, int n_in,
                              void* d_out, int out_size, void* d_ws, size_t ws_size,
                              hipStream_t stream) {
    const float* x     = (const float*)d_in[0];
    const float* w_ds  = (const float*)d_in[1];
    const float* wq    = (const float*)d_in[2];
    const float* bq    = (const float*)d_in[3];
    const float* wk    = (const float*)d_in[4];
    const float* bk    = (const float*)d_in[5];
    const float* wv    = (const float*)d_in[6];
    const float* bv    = (const float*)d_in[7];
    const float* rel_h = (const float*)d_in[8];
    const float* rel_w = (const float*)d_in[9];
    const float* ln_w  = (const float*)d_in[10];
    const float* ln_b  = (const float*)d_in[11];
    const float* w1    = (const float*)d_in[12];
    float* out = (float*)d_out;

    float* ws = (float*)d_ws;
    float* out0 = ws;                        // [B, P, N] fp32 (also attention output)
    float* wdst = ws + 4194304;              // [INC, P]
    float* wqt  = wdst + 262144;             // [P, P]
    float* wkt  = wqt + 65536;
    float* wvt  = wkt + 65536;
    float* w1t  = wvt + 65536;               // [P, INC]
    f16_t* ha = (f16_t*)(w1t + 262144);
    f16_t* q_t   = ha;                       // [B*H][N][64]
    f16_t* k_t   = ha + 4194304;             // [B*H][N][64]
    f16_t* v_b   = ha + 8388608;             // [B*H][64][N]
    f16_t* pos_t = ha + 12582912;            // [H][N][64]

    transpose_k<<<(PP * INC + 255) / 256, 256, 0, stream>>>(w_ds, wdst, PP, INC);
    transpose_k<<<(PP * PP + 255) / 256, 256, 0, stream>>>(wq, wqt, PP, PP);
    transpose_k<<<(PP * PP + 255) / 256, 256, 0, stream>>>(wk, wkt, PP, PP);
    transpose_k<<<(PP * PP + 255) / 256, 256, 0, stream>>>(wv, wvt, PP, PP);
    transpose_k<<<(INC * PP + 255) / 256, 256, 0, stream>>>(w1, w1t, INC, PP);
    pos_k<<<1024, 256, 0, stream>>>(rel_h, rel_w, pos_t);

    // out0 = w_ds * x  (fp32)
    gemm_k<<<dim3(16, 4, 16), 256, 0, stream>>>(wdst, x, nullptr, nullptr, out0, nullptr, PP, NN, INC, 0);
    // q,k -> f16 [b][h][n][d]; v -> f16 [b][p][n]
    gemm_k<<<dim3(16, 4, 16), 256, 0, stream>>>(wqt, out0, bq, nullptr, nullptr, q_t, PP, NN, PP, 1);
    gemm_k<<<dim3(16, 4, 16), 256, 0, stream>>>(wkt, out0, bk, nullptr, nullptr, k_t, PP, NN, PP, 1);
    gemm_k<<<dim3(16, 4, 16), 256, 0, stream>>>(wvt, out0, bv, nullptr, nullptr, v_b, PP, NN, PP, 3);
    // attention -> out0 (fp32, reuse)
    attn_mfma<<<dim3(16, 4, 16), 256, 0, stream>>>(q_t, k_t, v_b, pos_t, out0);
    // layernorm in-place
    ln_k<<<dim3(32, 16), 256, 0, stream>>>(out0, ln_w, ln_b);
    // out = gelu(w1 * y) + x
    gemm_k<<<dim3(16, 16, 16), 256, 0, stream>>>(w1t, out0, nullptr, x, out, nullptr, INC, NN, PP, 2);
}

// Round 4
// 519.997 us; speedup vs baseline: 3.9212x; 1.2836x over previous
//
#include <hip/hip_runtime.h>
#include <hip/hip_bf16.h>
#include <math.h>

#define BB 16
#define INC 1024
#define PP 256
#define NHEADS 4
#define DD 64
#define NN 1024

typedef _Float16 f16_t;
typedef __attribute__((ext_vector_type(8))) _Float16 f16x8;
typedef __attribute__((ext_vector_type(4))) _Float16 f16x4;
typedef __attribute__((ext_vector_type(4))) float f32x4;

__device__ __forceinline__ float gelu_exact(float v) {
    return 0.5f * v * (1.0f + erff(v * 0.70710678118654752440f));
}

// f32 -> f16 elementwise, vectorized by 4
__global__ void cast4_k(const float* __restrict__ src, f16_t* __restrict__ dst, int n4) {
    int i = blockIdx.x * 256 + threadIdx.x;
    if (i < n4) {
        float4 v = ((const float4*)src)[i];
        f16x4 o = {(f16_t)v.x, (f16_t)v.y, (f16_t)v.z, (f16_t)v.w};
        ((f16x4*)dst)[i] = o;
    }
}

// x [B][C=1024][N=1024] f32  ->  xt [B][N][C] f16
__global__ __launch_bounds__(256) void transpose_xk(const float* __restrict__ x,
                                                    f16_t* __restrict__ xt) {
    __shared__ float T[64][65];
    int tid = threadIdx.x;
    int tn = tid & 63, tr = tid >> 6;            // tr 0..3
    int n0 = blockIdx.x * 64, c0 = blockIdx.y * 64;
    size_t b = blockIdx.z;
    const float* xp = x + b * 1048576;
    f16_t* xo = xt + b * 1048576;
    #pragma unroll
    for (int rr = 0; rr < 64; rr += 4)
        T[tr + rr][tn] = xp[(size_t)(c0 + tr + rr) * 1024 + n0 + tn];
    __syncthreads();
    #pragma unroll
    for (int rr = 0; rr < 64; rr += 4)
        xo[(size_t)(n0 + tr + rr) * 1024 + c0 + tn] = (f16_t)T[tn][tr + rr];
}

// pos_t[h][i][d] = rel_h[h][d][i&31] + rel_w[h][d][i>>5]  (f16)
__global__ void pos_k(const float* __restrict__ rel_h, const float* __restrict__ rel_w,
                      f16_t* __restrict__ pos_t) {
    int idx = blockIdx.x * 256 + threadIdx.x;     // 4*1024*64
    int d = idx & 63;
    int i = (idx >> 6) & 1023;
    int h = idx >> 16;
    float v = rel_h[(h * 64 + d) * 32 + (i & 31)] + rel_w[(h * 64 + d) * 32 + (i >> 5)];
    pos_t[idx] = (f16_t)v;
}

// MFMA GEMM: C[b][m][n] = sum_k A[m][k] * Bt[b][n][k] (+bias[m]).
// A: [M][K] f16 (weights). Bt: per-batch [N][K] f16.
// Block = 128m x 128n, 4 waves; wave wv covers n-slice n0+wv*32, all 128 m.
// mode 0: Ch[(b*N+n)*M + m] f16 (no bias)                    [out0_t]
// mode 1: Ch[((b*4+h)*1024+n)*64 + d] f16, +bias (h=m>>6)    [q_t/k_t]
// mode 2: Ch[((b*4+h)*64+d)*1024 + n] f16, +bias             [v_b]
// mode 3: Cf[(b*M+m)*N+n] = gelu(acc)+resid  f32             [final]
__global__ __launch_bounds__(256) void hgemm(
    const f16_t* __restrict__ A, const f16_t* __restrict__ Bt,
    const float* __restrict__ bias, const float* __restrict__ resid,
    f16_t* __restrict__ Ch, float* __restrict__ Cf,
    int M, int N, int K, int mode)
{
    int tid = threadIdx.x;
    int wv = tid >> 6;
    int l = tid & 63;
    int lo = l & 15, hi = l >> 4;
    int m0 = blockIdx.y * 128;
    int n0 = blockIdx.x * 128 + wv * 32;
    size_t b = blockIdx.z;

    const f16_t* Ap = A + (size_t)(m0 + lo) * K + hi * 8;
    const f16_t* Bq = Bt + b * (size_t)N * K + (size_t)(n0 + lo) * K + hi * 8;

    f32x4 acc[8][2] = {};

    #pragma unroll 2
    for (int k0 = 0; k0 < K; k0 += 32) {
        f16x8 bfr0 = *(const f16x8*)(Bq + k0);
        f16x8 bfr1 = *(const f16x8*)(Bq + (size_t)16 * K + k0);
        #pragma unroll
        for (int fm = 0; fm < 8; ++fm) {
            f16x8 af = *(const f16x8*)(Ap + (size_t)fm * 16 * K + k0);
            acc[fm][0] = __builtin_amdgcn_mfma_f32_16x16x32_f16(af, bfr0, acc[fm][0], 0, 0, 0);
            acc[fm][1] = __builtin_amdgcn_mfma_f32_16x16x32_f16(af, bfr1, acc[fm][1], 0, 0, 0);
        }
    }

    #pragma unroll
    for (int fn = 0; fn < 2; ++fn) {
        int n = n0 + fn * 16 + lo;
        #pragma unroll
        for (int fm = 0; fm < 8; ++fm) {
            int mb = m0 + fm * 16 + hi * 4;
            f32x4 a = acc[fm][fn];
            if (mode == 0) {
                f16x4 st;
                #pragma unroll
                for (int r = 0; r < 4; ++r) st[r] = (f16_t)a[r];
                *(f16x4*)&Ch[((size_t)b * N + n) * M + mb] = st;
            } else if (mode == 1) {
                int h = mb >> 6, d0 = mb & 63;
                f16x4 st;
                #pragma unroll
                for (int r = 0; r < 4; ++r) st[r] = (f16_t)(a[r] + bias[mb + r]);
                *(f16x4*)&Ch[(((size_t)b * 4 + h) * 1024 + n) * 64 + d0] = st;
            } else if (mode == 2) {
                int h = mb >> 6, d0 = mb & 63;
                #pragma unroll
                for (int r = 0; r < 4; ++r)
                    Ch[(((size_t)b * 4 + h) * 64 + d0 + r) * 1024 + n] = (f16_t)(a[r] + bias[mb + r]);
            } else {
                #pragma unroll
                for (int r = 0; r < 4; ++r) {
                    size_t idx = ((size_t)b * M + mb + r) * N + n;
                    Cf[idx] = gelu_exact(a[r]) + resid[idx];
                }
            }
        }
    }
}

// MFMA flash attention (fp16 operands, fp32 accum).
// q_t,k_t: [B*H][N][64]. v_b: [B*H][64][N]. pos_t: [H][N][64].
// o: [B][N][256] fp32  (p = h*64+d)
__global__ __launch_bounds__(256) void attn_mfma(
    const f16_t* __restrict__ q_t, const f16_t* __restrict__ k_t,
    const f16_t* __restrict__ v_b, const f16_t* __restrict__ pos_t,
    float* __restrict__ o)
{
    __shared__ __align__(16) char plds[4][2048];  // per-wave P tile 16x64 f16, swizzled
    int tid = threadIdx.x;
    int wv = tid >> 6;
    int l = tid & 63;
    int lo = l & 15, hi = l >> 4;
    int h = blockIdx.y, b = blockIdx.z;
    int bh = b * 4 + h;
    int i_row = blockIdx.x * 64 + wv * 16;
    size_t qbase = (size_t)bh * 1024 * 64;

    f16x8 afr[4];
    {
        const f16_t* qr = q_t + qbase + (size_t)(i_row + lo) * 64 + hi * 8;
        afr[0] = *(const f16x8*)(qr);
        afr[1] = *(const f16x8*)(qr + 32);
        const f16_t* pr = pos_t + ((size_t)h * 1024 + i_row + lo) * 64 + hi * 8;
        afr[2] = *(const f16x8*)(pr);
        afr[3] = *(const f16x8*)(pr + 32);
    }

    f32x4 acc_o[4] = {};
    float m_run[4], l_run[4];
    #pragma unroll
    for (int r = 0; r < 4; ++r) { m_run[r] = -1e30f; l_run[r] = 0.0f; }

    char* pw = plds[wv];

    for (int j0 = 0; j0 < NN; j0 += 64) {
        f32x4 s[4] = {};
        #pragma unroll
        for (int ks = 0; ks < 4; ++ks) {
            const f16_t* kb = (ks < 2 ? k_t : q_t) + qbase + (size_t)(ks & 1) * 32 + hi * 8;
            #pragma unroll
            for (int f = 0; f < 4; ++f) {
                f16x8 bf = *(const f16x8*)(kb + (size_t)(j0 + f * 16 + lo) * 64);
                s[f] = __builtin_amdgcn_mfma_f32_16x16x32_f16(afr[ks], bf, s[f], 0, 0, 0);
            }
        }
        float mnew[4];
        #pragma unroll
        for (int r = 0; r < 4; ++r) {
            float m = fmaxf(fmaxf(s[0][r], s[1][r]), fmaxf(s[2][r], s[3][r]));
            #pragma unroll
            for (int off = 1; off < 16; off <<= 1) m = fmaxf(m, __shfl_xor(m, off, 64));
            mnew[r] = fmaxf(m_run[r], m);
        }
        float rsum[4] = {0.f, 0.f, 0.f, 0.f};
        #pragma unroll
        for (int f = 0; f < 4; ++f) {
            #pragma unroll
            for (int r = 0; r < 4; ++r) {
                float p = __expf(s[f][r] - mnew[r]);
                s[f][r] = p;
                rsum[r] += p;
            }
        }
        #pragma unroll
        for (int r = 0; r < 4; ++r) {
            #pragma unroll
            for (int off = 1; off < 16; off <<= 1) rsum[r] += __shfl_xor(rsum[r], off, 64);
            float alpha = __expf(m_run[r] - mnew[r]);
            l_run[r] = l_run[r] * alpha + rsum[r];
            m_run[r] = mnew[r];
            #pragma unroll
            for (int f = 0; f < 4; ++f) acc_o[f][r] *= alpha;
        }
        #pragma unroll
        for (int f = 0; f < 4; ++f) {
            #pragma unroll
            for (int r = 0; r < 4; ++r) {
                int row = hi * 4 + r;
                int cb = (f * 16 + lo) * 2;
                *(f16_t*)(pw + row * 128 + (cb ^ ((row & 7) << 4))) = (f16_t)s[f][r];
            }
        }
        __syncthreads();
        const f16_t* vb = v_b + qbase + (size_t)lo * 1024 + j0 + hi * 8;
        #pragma unroll
        for (int ks = 0; ks < 2; ++ks) {
            f16x8 pa = *(const f16x8*)(pw + lo * 128 + ((ks * 64 + hi * 16) ^ ((lo & 7) << 4)));
            #pragma unroll
            for (int f = 0; f < 4; ++f) {
                f16x8 vf = *(const f16x8*)(vb + (size_t)f * 16 * 1024 + ks * 32);
                acc_o[f] = __builtin_amdgcn_mfma_f32_16x16x32_f16(pa, vf, acc_o[f], 0, 0, 0);
            }
        }
        __syncthreads();
    }

    // store O -> o[b][n][p], p = h*64 + (f*16+lo), n = i_row+hi*4+r
    #pragma unroll
    for (int r = 0; r < 4; ++r) {
        float inv = 1.0f / l_run[r];
        #pragma unroll
        for (int f = 0; f < 4; ++f) {
            o[((size_t)b * 1024 + i_row + hi * 4 + r) * 256 + h * 64 + f * 16 + lo] = acc_o[f][r] * inv;
        }
    }
}

// LayerNorm over P=256: o [B][N][256] f32 -> yt [B][N][256] f16. One wave per row.
__global__ __launch_bounds__(256) void ln_k(const float* __restrict__ o,
                                            f16_t* __restrict__ yt,
                                            const float* __restrict__ lw,
                                            const float* __restrict__ lb)
{
    int tid = threadIdx.x;
    int wv = tid >> 6, l = tid & 63;
    size_t row = (size_t)blockIdx.x * 4 + wv;
    f32x4 v = ((const f32x4*)(o + row * 256))[l];
    float s = v[0] + v[1] + v[2] + v[3];
    float q = v[0]*v[0] + v[1]*v[1] + v[2]*v[2] + v[3]*v[3];
    #pragma unroll
    for (int off = 1; off < 64; off <<= 1) {
        s += __shfl_xor(s, off, 64);
        q += __shfl_xor(q, off, 64);
    }
    float mean = s * (1.0f / 256.0f);
    float var = q * (1.0f / 256.0f) - mean * mean;
    float rstd = rsqrtf(var + 1e-6f);
    f32x4 w4 = ((const f32x4*)lw)[l];
    f32x4 b4 = ((const f32x4*)lb)[l];
    f16x4 o4;
    #pragma unroll
    for (int j = 0; j < 4; ++j)
        o4[j] = (f16_t)((v[j] - mean) * rstd * w4[j] + b4[j]);
    ((f16x4*)(yt + row * 256))[l] = o4;
}

extern "C" void kernel_launch(void* const* d_in, const int* in_sizes, int n_in,
                              void* d_out, int out_size, void* d_ws, size_t ws_size,
                              hipStream_t stream) {
    const float* x     = (const float*)d_in[0];
    const float* w_ds  = (const float*)d_in[1];
    const float* wq    = (const float*)d_in[2];
    const float* bq    = (const float*)d_in[3];
    const float* wk    = (const float*)d_in[4];
    const float* bk    = (const float*)d_in[5];
    const float* wv    = (const float*)d_in[6];
    const float* bv    = (const float*)d_in[7];
    const float* rel_h = (const float*)d_in[8];
    const float* rel_w = (const float*)d_in[9];
    const float* ln_w  = (const float*)d_in[10];
    const float* ln_b  = (const float*)d_in[11];
    const float* w1    = (const float*)d_in[12];
    float* out = (float*)d_out;

    f16_t* xt    = (f16_t*)d_ws;             // [B][N][C]   32 MB
    f16_t* wdsh  = xt + 16777216;            // [256][1024] 512 KB
    f16_t* wqh   = wdsh + 262144;            // [256][256]
    f16_t* wkh   = wqh + 65536;
    f16_t* wvh   = wkh + 65536;
    f16_t* w1h   = wvh + 65536;              // [1024][256] 512 KB
    f16_t* post  = w1h + 262144;             // [4][1024][64] 512 KB
    f16_t* out0t = post + 262144;            // [B][N][256] 8 MB
    f16_t* qt    = out0t + 4194304;          // [B*4][N][64] 8 MB
    f16_t* kt    = qt + 4194304;
    f16_t* vb    = kt + 4194304;             // [B*4][64][N] 8 MB
    f16_t* ytb   = vb + 4194304;             // [B][N][256] 8 MB
    float* ot    = (float*)(ytb + 4194304);  // [B][N][256] f32 16 MB

    cast4_k<<<256, 256, 0, stream>>>(w_ds, wdsh, 65536);
    cast4_k<<<64, 256, 0, stream>>>(wq, wqh, 16384);
    cast4_k<<<64, 256, 0, stream>>>(wk, wkh, 16384);
    cast4_k<<<64, 256, 0, stream>>>(wv, wvh, 16384);
    cast4_k<<<256, 256, 0, stream>>>(w1, w1h, 65536);
    pos_k<<<1024, 256, 0, stream>>>(rel_h, rel_w, post);
    transpose_xk<<<dim3(16, 16, 16), 256, 0, stream>>>(x, xt);

    // out0_t[b][n][p] = w_ds * x
    hgemm<<<dim3(8, 2, 16), 256, 0, stream>>>(wdsh, xt, nullptr, nullptr, out0t, nullptr, PP, NN, INC, 0);
    // q,k -> [bh][n][d]; v -> [bh][d][n]
    hgemm<<<dim3(8, 2, 16), 256, 0, stream>>>(wqh, out0t, bq, nullptr, qt, nullptr, PP, NN, PP, 1);
    hgemm<<<dim3(8, 2, 16), 256, 0, stream>>>(wkh, out0t, bk, nullptr, kt, nullptr, PP, NN, PP, 1);
    hgemm<<<dim3(8, 2, 16), 256, 0, stream>>>(wvh, out0t, bv, nullptr, vb, nullptr, PP, NN, PP, 2);
    // attention -> ot [b][n][256] f32
    attn_mfma<<<dim3(16, 4, 16), 256, 0, stream>>>(qt, kt, vb, post, ot);
    // layernorm -> ytb f16
    ln_k<<<4096, 256, 0, stream>>>(ot, ytb, ln_w, ln_b);
    // out = gelu(w1 * y) + x
    hgemm<<<dim3(8, 8, 16), 256, 0, stream>>>(w1h, ytb, nullptr, x, nullptr, out, INC, NN, PP, 3);
}

// Round 5
// 409.450 us; speedup vs baseline: 4.9799x; 1.2700x over previous
//
#include <hip/hip_runtime.h>
#include <hip/hip_bf16.h>
#include <math.h>

#define BB 16
#define INC 1024
#define PP 256
#define NHEADS 4
#define DD 64
#define NN 1024

typedef _Float16 f16_t;
typedef __attribute__((ext_vector_type(8))) _Float16 f16x8;
typedef __attribute__((ext_vector_type(4))) _Float16 f16x4;
typedef __attribute__((ext_vector_type(4))) float f32x4;

__device__ __forceinline__ float gelu_exact(float v) {
    return 0.5f * v * (1.0f + erff(v * 0.70710678118654752440f));
}

// f32 -> f16 elementwise, vectorized by 4
__global__ void cast4_k(const float* __restrict__ src, f16_t* __restrict__ dst, int n4) {
    int i = blockIdx.x * 256 + threadIdx.x;
    if (i < n4) {
        float4 v = ((const float4*)src)[i];
        f16x4 o = {(f16_t)v.x, (f16_t)v.y, (f16_t)v.z, (f16_t)v.w};
        ((f16x4*)dst)[i] = o;
    }
}

// x [B][C=1024][N=1024] f32  ->  xt [B][N][C] f16
__global__ __launch_bounds__(256) void transpose_xk(const float* __restrict__ x,
                                                    f16_t* __restrict__ xt) {
    __shared__ float T[64][65];
    int tid = threadIdx.x;
    int tn = tid & 63, tr = tid >> 6;            // tr 0..3
    int n0 = blockIdx.x * 64, c0 = blockIdx.y * 64;
    size_t b = blockIdx.z;
    const float* xp = x + b * 1048576;
    f16_t* xo = xt + b * 1048576;
    #pragma unroll
    for (int rr = 0; rr < 64; rr += 4)
        T[tr + rr][tn] = xp[(size_t)(c0 + tr + rr) * 1024 + n0 + tn];
    __syncthreads();
    #pragma unroll
    for (int rr = 0; rr < 64; rr += 4)
        xo[(size_t)(n0 + tr + rr) * 1024 + c0 + tn] = (f16_t)T[tn][tr + rr];
}

// pos_t[h][i][d] = rel_h[h][d][i&31] + rel_w[h][d][i>>5]  (f16)
__global__ void pos_k(const float* __restrict__ rel_h, const float* __restrict__ rel_w,
                      f16_t* __restrict__ pos_t) {
    int idx = blockIdx.x * 256 + threadIdx.x;     // 4*1024*64
    int d = idx & 63;
    int i = (idx >> 6) & 1023;
    int h = idx >> 16;
    float v = rel_h[(h * 64 + d) * 32 + (i & 31)] + rel_w[(h * 64 + d) * 32 + (i >> 5)];
    pos_t[idx] = (f16_t)v;
}

// MFMA GEMM, ONE WAVE per block: 64m x 32n per wave.
// C[b][m][n] = sum_k A[m][k] * Bt[b][n][k] (+bias[m]).
// A: [M][K] f16 (weights row-major). Bt: per-batch [N][K] f16.
// mode 0: Ch[(b*N+n)*M + m] f16 (no bias)                    [out0_t]
// mode 1: Ch[((b*4+h)*1024+n)*64 + d] f16, +bias (h=m>>6)    [q_t/k_t]
// mode 2: Ch[((b*4+h)*64+d)*1024 + n] f16, +bias             [v_b]
// mode 3: Cf[(b*M+m)*N+n] = gelu(acc)+resid  f32             [final]
__global__ __launch_bounds__(64) void hgemm(
    const f16_t* __restrict__ A, const f16_t* __restrict__ Bt,
    const float* __restrict__ bias, const float* __restrict__ resid,
    f16_t* __restrict__ Ch, float* __restrict__ Cf,
    int M, int N, int K, int mode)
{
    int l = threadIdx.x;
    int lo = l & 15, hi = l >> 4;
    int m0 = blockIdx.y * 64;
    int n0 = blockIdx.x * 32;
    size_t b = blockIdx.z;

    const f16_t* Ap = A + (size_t)(m0 + lo) * K + hi * 8;
    const f16_t* Bq = Bt + b * (size_t)N * K + (size_t)(n0 + lo) * K + hi * 8;

    f32x4 acc[4][2] = {};

    #pragma unroll 2
    for (int k0 = 0; k0 < K; k0 += 32) {
        f16x8 bfr0 = *(const f16x8*)(Bq + k0);
        f16x8 bfr1 = *(const f16x8*)(Bq + (size_t)16 * K + k0);
        #pragma unroll
        for (int fm = 0; fm < 4; ++fm) {
            f16x8 af = *(const f16x8*)(Ap + (size_t)fm * 16 * K + k0);
            acc[fm][0] = __builtin_amdgcn_mfma_f32_16x16x32_f16(af, bfr0, acc[fm][0], 0, 0, 0);
            acc[fm][1] = __builtin_amdgcn_mfma_f32_16x16x32_f16(af, bfr1, acc[fm][1], 0, 0, 0);
        }
    }

    #pragma unroll
    for (int fn = 0; fn < 2; ++fn) {
        int n = n0 + fn * 16 + lo;
        #pragma unroll
        for (int fm = 0; fm < 4; ++fm) {
            int mb = m0 + fm * 16 + hi * 4;
            f32x4 a = acc[fm][fn];
            if (mode == 0) {
                f16x4 st;
                #pragma unroll
                for (int r = 0; r < 4; ++r) st[r] = (f16_t)a[r];
                *(f16x4*)&Ch[((size_t)b * N + n) * M + mb] = st;
            } else if (mode == 1) {
                int h = mb >> 6, d0 = mb & 63;
                f16x4 st;
                #pragma unroll
                for (int r = 0; r < 4; ++r) st[r] = (f16_t)(a[r] + bias[mb + r]);
                *(f16x4*)&Ch[(((size_t)b * 4 + h) * 1024 + n) * 64 + d0] = st;
            } else if (mode == 2) {
                int h = mb >> 6, d0 = mb & 63;
                #pragma unroll
                for (int r = 0; r < 4; ++r)
                    Ch[(((size_t)b * 4 + h) * 64 + d0 + r) * 1024 + n] = (f16_t)(a[r] + bias[mb + r]);
            } else {
                #pragma unroll
                for (int r = 0; r < 4; ++r) {
                    size_t idx = ((size_t)b * M + mb + r) * N + n;
                    Cf[idx] = gelu_exact(a[r]) + resid[idx];
                }
            }
        }
    }
}

// MFMA flash attention, ONE WAVE per block, 32 q-rows per wave (2 fragment sets).
// q_t,k_t: [B*H][N][64]. v_b: [B*H][64][N]. pos_t: [H][N][64].
// o: [B][N][256] fp32  (p = h*64+d)
// S[i][j] = sum_{d<64} q[i][d]k[j][d] + sum_{d<64} pos[i][d]q[j][d]
__global__ __launch_bounds__(64) void attn_mfma(
    const f16_t* __restrict__ q_t, const f16_t* __restrict__ k_t,
    const f16_t* __restrict__ v_b, const f16_t* __restrict__ pos_t,
    float* __restrict__ o)
{
    __shared__ __align__(16) char plds[2][2048];  // per-set P tile 16x64 f16, swizzled
    int l = threadIdx.x;
    int lo = l & 15, hi = l >> 4;
    int h = blockIdx.y, b = blockIdx.z;
    int bh = b * 4 + h;
    int i_row = blockIdx.x * 32;
    size_t qbase = (size_t)bh * 1024 * 64;

    // A fragments: set s rows i_row+s*16+lo; ks: 0,1 = q d0-31/d32-63; 2,3 = pos
    f16x8 afr[2][4];
    #pragma unroll
    for (int s = 0; s < 2; ++s) {
        const f16_t* qr = q_t + qbase + (size_t)(i_row + s * 16 + lo) * 64 + hi * 8;
        afr[s][0] = *(const f16x8*)(qr);
        afr[s][1] = *(const f16x8*)(qr + 32);
        const f16_t* pr = pos_t + ((size_t)h * 1024 + i_row + s * 16 + lo) * 64 + hi * 8;
        afr[s][2] = *(const f16x8*)(pr);
        afr[s][3] = *(const f16x8*)(pr + 32);
    }

    f32x4 acc_o[2][4] = {};
    float m_run[2][4], l_run[2][4];
    #pragma unroll
    for (int s = 0; s < 2; ++s)
        #pragma unroll
        for (int r = 0; r < 4; ++r) { m_run[s][r] = -1e30f; l_run[s][r] = 0.0f; }

    for (int j0 = 0; j0 < NN; j0 += 64) {
        f32x4 sc[2][4] = {};
        #pragma unroll
        for (int ks = 0; ks < 4; ++ks) {
            const f16_t* kb = (ks < 2 ? k_t : q_t) + qbase + (size_t)(ks & 1) * 32 + hi * 8;
            #pragma unroll
            for (int f = 0; f < 4; ++f) {
                f16x8 bf = *(const f16x8*)(kb + (size_t)(j0 + f * 16 + lo) * 64);
                sc[0][f] = __builtin_amdgcn_mfma_f32_16x16x32_f16(afr[0][ks], bf, sc[0][f], 0, 0, 0);
                sc[1][f] = __builtin_amdgcn_mfma_f32_16x16x32_f16(afr[1][ks], bf, sc[1][f], 0, 0, 0);
            }
        }
        // online softmax per set; C layout: row = hi*4+r (q), col = 16f+lo (j)
        #pragma unroll
        for (int s = 0; s < 2; ++s) {
            float mnew[4];
            #pragma unroll
            for (int r = 0; r < 4; ++r) {
                float m = fmaxf(fmaxf(sc[s][0][r], sc[s][1][r]), fmaxf(sc[s][2][r], sc[s][3][r]));
                #pragma unroll
                for (int off = 1; off < 16; off <<= 1) m = fmaxf(m, __shfl_xor(m, off, 64));
                mnew[r] = fmaxf(m_run[s][r], m);
            }
            float rsum[4] = {0.f, 0.f, 0.f, 0.f};
            #pragma unroll
            for (int f = 0; f < 4; ++f) {
                #pragma unroll
                for (int r = 0; r < 4; ++r) {
                    float p = __expf(sc[s][f][r] - mnew[r]);
                    sc[s][f][r] = p;
                    rsum[r] += p;
                }
            }
            #pragma unroll
            for (int r = 0; r < 4; ++r) {
                #pragma unroll
                for (int off = 1; off < 16; off <<= 1) rsum[r] += __shfl_xor(rsum[r], off, 64);
                float alpha = __expf(m_run[s][r] - mnew[r]);
                l_run[s][r] = l_run[s][r] * alpha + rsum[r];
                m_run[s][r] = mnew[r];
                #pragma unroll
                for (int f = 0; f < 4; ++f) acc_o[s][f][r] *= alpha;
            }
            // P -> LDS (f16, XOR-swizzled rows)
            char* pw = plds[s];
            #pragma unroll
            for (int f = 0; f < 4; ++f) {
                #pragma unroll
                for (int r = 0; r < 4; ++r) {
                    int row = hi * 4 + r;
                    int cb = (f * 16 + lo) * 2;
                    *(f16_t*)(pw + row * 128 + (cb ^ ((row & 7) << 4))) = (f16_t)sc[s][f][r];
                }
            }
        }
        // wave-private LDS: no s_barrier needed, just drain DS before reading
        asm volatile("s_waitcnt lgkmcnt(0)" ::: "memory");
        __builtin_amdgcn_sched_barrier(0);
        // PV: A = P (lane row = lo), B = V^T (lane col d = 16f+lo, k = j-local)
        const f16_t* vbp = v_b + qbase + (size_t)lo * 1024 + j0 + hi * 8;
        #pragma unroll
        for (int ks = 0; ks < 2; ++ks) {
            f16x8 pa0 = *(const f16x8*)(plds[0] + lo * 128 + ((ks * 64 + hi * 16) ^ ((lo & 7) << 4)));
            f16x8 pa1 = *(const f16x8*)(plds[1] + lo * 128 + ((ks * 64 + hi * 16) ^ ((lo & 7) << 4)));
            #pragma unroll
            for (int f = 0; f < 4; ++f) {
                f16x8 vf = *(const f16x8*)(vbp + (size_t)f * 16 * 1024 + ks * 32);
                acc_o[0][f] = __builtin_amdgcn_mfma_f32_16x16x32_f16(pa0, vf, acc_o[0][f], 0, 0, 0);
                acc_o[1][f] = __builtin_amdgcn_mfma_f32_16x16x32_f16(pa1, vf, acc_o[1][f], 0, 0, 0);
            }
        }
        asm volatile("s_waitcnt lgkmcnt(0)" ::: "memory");
        __builtin_amdgcn_sched_barrier(0);
    }

    // store O -> o[b][n][p], p = h*64 + (f*16+lo), n = i_row + s*16 + hi*4+r
    #pragma unroll
    for (int s = 0; s < 2; ++s) {
        #pragma unroll
        for (int r = 0; r < 4; ++r) {
            float inv = 1.0f / l_run[s][r];
            int n = i_row + s * 16 + hi * 4 + r;
            #pragma unroll
            for (int f = 0; f < 4; ++f) {
                o[((size_t)b * 1024 + n) * 256 + h * 64 + f * 16 + lo] = acc_o[s][f][r] * inv;
            }
        }
    }
}

// LayerNorm over P=256: o [B][N][256] f32 -> yt [B][N][256] f16. One wave per row.
__global__ __launch_bounds__(256) void ln_k(const float* __restrict__ o,
                                            f16_t* __restrict__ yt,
                                            const float* __restrict__ lw,
                                            const float* __restrict__ lb)
{
    int tid = threadIdx.x;
    int wv = tid >> 6, l = tid & 63;
    size_t row = (size_t)blockIdx.x * 4 + wv;
    f32x4 v = ((const f32x4*)(o + row * 256))[l];
    float s = v[0] + v[1] + v[2] + v[3];
    float q = v[0]*v[0] + v[1]*v[1] + v[2]*v[2] + v[3]*v[3];
    #pragma unroll
    for (int off = 1; off < 64; off <<= 1) {
        s += __shfl_xor(s, off, 64);
        q += __shfl_xor(q, off, 64);
    }
    float mean = s * (1.0f / 256.0f);
    float var = q * (1.0f / 256.0f) - mean * mean;
    float rstd = rsqrtf(var + 1e-6f);
    f32x4 w4 = ((const f32x4*)lw)[l];
    f32x4 b4 = ((const f32x4*)lb)[l];
    f16x4 o4;
    #pragma unroll
    for (int j = 0; j < 4; ++j)
        o4[j] = (f16_t)((v[j] - mean) * rstd * w4[j] + b4[j]);
    ((f16x4*)(yt + row * 256))[l] = o4;
}

extern "C" void kernel_launch(void* const* d_in, const int* in_sizes, int n_in,
                              void* d_out, int out_size, void* d_ws, size_t ws_size,
                              hipStream_t stream) {
    const float* x     = (const float*)d_in[0];
    const float* w_ds  = (const float*)d_in[1];
    const float* wq    = (const float*)d_in[2];
    const float* bq    = (const float*)d_in[3];
    const float* wk    = (const float*)d_in[4];
    const float* bk    = (const float*)d_in[5];
    const float* wv    = (const float*)d_in[6];
    const float* bv    = (const float*)d_in[7];
    const float* rel_h = (const float*)d_in[8];
    const float* rel_w = (const float*)d_in[9];
    const float* ln_w  = (const float*)d_in[10];
    const float* ln_b  = (const float*)d_in[11];
    const float* w1    = (const float*)d_in[12];
    float* out = (float*)d_out;

    f16_t* xt    = (f16_t*)d_ws;             // [B][N][C]   32 MB
    f16_t* wdsh  = xt + 16777216;            // [256][1024] 512 KB
    f16_t* wqh   = wdsh + 262144;            // [256][256]
    f16_t* wkh   = wqh + 65536;
    f16_t* wvh   = wkh + 65536;
    f16_t* w1h   = wvh + 65536;              // [1024][256] 512 KB
    f16_t* post  = w1h + 262144;             // [4][1024][64] 512 KB
    f16_t* out0t = post + 262144;            // [B][N][256] 8 MB
    f16_t* qt    = out0t + 4194304;          // [B*4][N][64] 8 MB
    f16_t* kt    = qt + 4194304;
    f16_t* vb    = kt + 4194304;             // [B*4][64][N] 8 MB
    f16_t* ytb   = vb + 4194304;             // [B][N][256] 8 MB
    float* ot    = (float*)(ytb + 4194304);  // [B][N][256] f32 16 MB

    cast4_k<<<256, 256, 0, stream>>>(w_ds, wdsh, 65536);
    cast4_k<<<64, 256, 0, stream>>>(wq, wqh, 16384);
    cast4_k<<<64, 256, 0, stream>>>(wk, wkh, 16384);
    cast4_k<<<64, 256, 0, stream>>>(wv, wvh, 16384);
    cast4_k<<<256, 256, 0, stream>>>(w1, w1h, 65536);
    pos_k<<<1024, 256, 0, stream>>>(rel_h, rel_w, post);
    transpose_xk<<<dim3(16, 16, 16), 256, 0, stream>>>(x, xt);

    // out0_t[b][n][p] = w_ds * x
    hgemm<<<dim3(32, 4, 16), 64, 0, stream>>>(wdsh, xt, nullptr, nullptr, out0t, nullptr, PP, NN, INC, 0);
    // q,k -> [bh][n][d]; v -> [bh][d][n]
    hgemm<<<dim3(32, 4, 16), 64, 0, stream>>>(wqh, out0t, bq, nullptr, qt, nullptr, PP, NN, PP, 1);
    hgemm<<<dim3(32, 4, 16), 64, 0, stream>>>(wkh, out0t, bk, nullptr, kt, nullptr, PP, NN, PP, 1);
    hgemm<<<dim3(32, 4, 16), 64, 0, stream>>>(wvh, out0t, bv, nullptr, vb, nullptr, PP, NN, PP, 2);
    // attention -> ot [b][n][256] f32
    attn_mfma<<<dim3(32, 4, 16), 64, 0, stream>>>(qt, kt, vb, post, ot);
    // layernorm -> ytb f16
    ln_k<<<4096, 256, 0, stream>>>(ot, ytb, ln_w, ln_b);
    // out = gelu(w1 * y) + x
    hgemm<<<dim3(32, 16, 16), 64, 0, stream>>>(w1h, ytb, nullptr, x, nullptr, out, INC, NN, PP, 3);
}

// Round 6
// 396.557 us; speedup vs baseline: 5.1418x; 1.0325x over previous
//
#include <hip/hip_runtime.h>
#include <hip/hip_bf16.h>
#include <math.h>

#define NN 1024
#define PP 256
#define INC 1024

typedef _Float16 f16_t;
typedef __attribute__((ext_vector_type(8))) _Float16 f16x8;
typedef __attribute__((ext_vector_type(4))) _Float16 f16x4;
typedef __attribute__((ext_vector_type(4))) float f32x4;
typedef __attribute__((ext_vector_type(16))) float f32x16;
typedef __attribute__((ext_vector_type(4))) int i32x4;

__device__ __forceinline__ float gelu_exact(float v) {
    return 0.5f * v * (1.0f + erff(v * 0.70710678118654752440f));
}

__device__ __forceinline__ void cvt_store(const float* __restrict__ s,
                                          f16_t* __restrict__ d, int j) {
    float4 v = ((const float4*)s)[j];
    f16x4 o = {(f16_t)v.x, (f16_t)v.y, (f16_t)v.z, (f16_t)v.w};
    ((f16x4*)d)[j] = o;
}

// One kernel: all weight casts + pos table + bias concat.
__global__ __launch_bounds__(256) void prep_k(
    const float* __restrict__ w_ds, const float* __restrict__ wq,
    const float* __restrict__ wk, const float* __restrict__ wv,
    const float* __restrict__ w1, const float* __restrict__ rel_h,
    const float* __restrict__ rel_w, const float* __restrict__ bq,
    const float* __restrict__ bk, const float* __restrict__ bv,
    f16_t* __restrict__ wdsh, f16_t* __restrict__ wqkv,
    f16_t* __restrict__ w1h, f16_t* __restrict__ post,
    float* __restrict__ bqkv)
{
    int i = blockIdx.x * 256 + threadIdx.x;
    if (i < 65536) {
        cvt_store(w_ds, wdsh, i);
    } else if (i < 81920) {
        cvt_store(wq, wqkv, i - 65536);
    } else if (i < 98304) {
        cvt_store(wk, wqkv + 65536, i - 81920);
    } else if (i < 114688) {
        cvt_store(wv, wqkv + 131072, i - 98304);
    } else if (i < 180224) {
        cvt_store(w1, w1h, i - 114688);
    } else if (i < 245760) {
        int j = i - 180224;
        int flat = j * 4;
        int d = flat & 63;
        int n = (flat >> 6) & 1023;
        int h = flat >> 16;
        f16x4 pk;
        #pragma unroll
        for (int jj = 0; jj < 4; ++jj) {
            float v = rel_h[(h * 64 + d + jj) * 32 + (n & 31)]
                    + rel_w[(h * 64 + d + jj) * 32 + (n >> 5)];
            pk[jj] = (f16_t)v;
        }
        *(f16x4*)&post[flat] = pk;
    } else if (i < 245952) {
        int j = i - 245760;
        int which = j >> 6, r = j & 63;
        const float* src = which == 0 ? bq : (which == 1 ? bk : bv);
        float4 v = ((const float4*)src)[r];
        ((float4*)bqkv)[which * 64 + r] = v;
    }
}

// x [B][C=1024][N=1024] f32  ->  xt [B][N][C] f16  (vectorized both sides)
__global__ __launch_bounds__(256) void transpose_xk(const float* __restrict__ x,
                                                    f16_t* __restrict__ xt) {
    __shared__ float T[64][68];
    int tid = threadIdx.x;
    int n0 = blockIdx.x * 64, c0 = blockIdx.y * 64;
    size_t b = blockIdx.z;
    const float* xp = x + b * 1048576;
    int cl = tid >> 4, n4 = (tid & 15) * 4;
    #pragma unroll
    for (int it = 0; it < 4; ++it) {
        float4 v = *(const float4*)&xp[(size_t)(c0 + cl + it * 16) * 1024 + n0 + n4];
        *(float4*)&T[cl + it * 16][n4] = v;
    }
    __syncthreads();
    int nl = tid >> 3, ck = tid & 7;
    f16_t* xo = xt + b * 1048576;
    #pragma unroll
    for (int it = 0; it < 2; ++it) {
        int n = nl + it * 32;
        f16x8 pk;
        #pragma unroll
        for (int j = 0; j < 8; ++j) pk[j] = (f16_t)T[ck * 8 + j][n];
        *(f16x8*)&xo[(size_t)(n0 + n) * 1024 + c0 + ck * 8] = pk;
    }
}

// MFMA GEMM, ONE WAVE per block: 64m x 32n.
// C[b][m][n] = sum_k A[m][k] * Bt[b][n][k] (+bias[m]).
// mode 0: Cq[(b*N+n)*M+m] f16 (out0_t). mode 1: merged qkv (M=768).
// mode 3: Cf = gelu(acc)+resid f32.
__global__ __launch_bounds__(64) void hgemm(
    const f16_t* __restrict__ A, const f16_t* __restrict__ Bt,
    const float* __restrict__ bias, const float* __restrict__ resid,
    f16_t* __restrict__ Cq, f16_t* __restrict__ Ck, f16_t* __restrict__ Cv,
    float* __restrict__ Cf,
    int M, int N, int K, int mode)
{
    int l = threadIdx.x;
    int lo = l & 15, hi = l >> 4;
    int m0 = blockIdx.y * 64;
    int n0 = blockIdx.x * 32;
    size_t bb = blockIdx.z;

    const f16_t* Ap = A + (size_t)(m0 + lo) * K + hi * 8;
    const f16_t* Bq = Bt + bb * (size_t)N * K + (size_t)(n0 + lo) * K + hi * 8;

    f32x4 acc[4][2] = {};

    #pragma unroll 2
    for (int k0 = 0; k0 < K; k0 += 32) {
        f16x8 bfr0 = *(const f16x8*)(Bq + k0);
        f16x8 bfr1 = *(const f16x8*)(Bq + (size_t)16 * K + k0);
        #pragma unroll
        for (int fm = 0; fm < 4; ++fm) {
            f16x8 af = *(const f16x8*)(Ap + (size_t)fm * 16 * K + k0);
            acc[fm][0] = __builtin_amdgcn_mfma_f32_16x16x32_f16(af, bfr0, acc[fm][0], 0, 0, 0);
            acc[fm][1] = __builtin_amdgcn_mfma_f32_16x16x32_f16(af, bfr1, acc[fm][1], 0, 0, 0);
        }
    }

    #pragma unroll
    for (int fn = 0; fn < 2; ++fn) {
        int n = n0 + fn * 16 + lo;
        #pragma unroll
        for (int fm = 0; fm < 4; ++fm) {
            int mb = m0 + fm * 16 + hi * 4;
            f32x4 a = acc[fm][fn];
            if (mode == 0) {
                f16x4 st;
                #pragma unroll
                for (int r = 0; r < 4; ++r) st[r] = (f16_t)a[r];
                *(f16x4*)&Cq[((size_t)bb * N + n) * M + mb] = st;
            } else if (mode == 1) {
                int which = mb >> 8;
                int mloc = mb & 255;
                int hh = mloc >> 6, d0 = mloc & 63;
                if (which == 2) {
                    #pragma unroll
                    for (int r = 0; r < 4; ++r)
                        Cv[(((size_t)bb * 4 + hh) * 64 + d0 + r) * NN + n] = (f16_t)(a[r] + bias[mb + r]);
                } else {
                    f16_t* dst = which ? Ck : Cq;
                    f16x4 st;
                    #pragma unroll
                    for (int r = 0; r < 4; ++r) st[r] = (f16_t)(a[r] + bias[mb + r]);
                    *(f16x4*)&dst[(((size_t)bb * 4 + hh) * NN + n) * 64 + d0] = st;
                }
            } else {
                #pragma unroll
                for (int r = 0; r < 4; ++r) {
                    size_t idx = ((size_t)bb * M + mb + r) * N + n;
                    Cf[idx] = gelu_exact(a[r]) + resid[idx];
                }
            }
        }
    }
}

// Swapped-operand 32x32 MFMA flash attention, ONE WAVE per block, 32 q per wave.
// q_t,k_t: [B*H][N][64]. v_b: [B*H][64][N]. pos_t: [H][N][64]. o: [B][N][256] f16.
// S^T[j][q] = q_q.k_j + pos_q.q_j ; lane owns q-column (col=lane&31) -> scalar softmax state.
__global__ __launch_bounds__(64) void attn_mfma(
    const f16_t* __restrict__ q_t, const f16_t* __restrict__ k_t,
    const f16_t* __restrict__ v_b, const f16_t* __restrict__ pos_t,
    f16_t* __restrict__ o)
{
    int l = threadIdx.x;
    int lq = l & 31;
    int half = l >> 5;
    int h = blockIdx.y, b = blockIdx.z;
    int q0 = blockIdx.x * 32;
    size_t base = (size_t)(b * 4 + h) * (NN * 64);

    // B-frags (hoisted): cols q = lq; k-chunks: 0-3 = q(d), 4-7 = pos(d)
    f16x8 Bq0, Bq1, Bq2, Bq3, Bq4, Bq5, Bq6, Bq7;
    {
        const f16_t* qr = q_t + base + (size_t)(q0 + lq) * 64 + half * 8;
        Bq0 = *(const f16x8*)(qr);
        Bq1 = *(const f16x8*)(qr + 16);
        Bq2 = *(const f16x8*)(qr + 32);
        Bq3 = *(const f16x8*)(qr + 48);
        const f16_t* pr = pos_t + ((size_t)h * NN + q0 + lq) * 64 + half * 8;
        Bq4 = *(const f16x8*)(pr);
        Bq5 = *(const f16x8*)(pr + 16);
        Bq6 = *(const f16x8*)(pr + 32);
        Bq7 = *(const f16x8*)(pr + 48);
    }

    f32x16 accD0 = {}, accD1 = {};   // O^T d-blocks 0-31 / 32-63, col q = lq
    float m_run = -1e30f, l_run = 0.0f;

    const f16_t* kbase = k_t + base + (size_t)lq * 64 + half * 8;
    const f16_t* qbase = q_t + base + (size_t)lq * 64 + half * 8;
    const f16_t* vbase = v_b + base + (size_t)lq * NN + half * 8;

    f16x8 aK0, aK1, aK2, aK3, aQ0, aQ1, aQ2, aQ3, aV00, aV01, aV10, aV11;
    f16x8 bK0, bK1, bK2, bK3, bQ0, bQ1, bQ2, bQ3, bV00, bV01, bV10, bV11;

#define LOADT(S, J) do { \
    const f16_t* ka_ = kbase + (size_t)(J) * 64; \
    S##K0 = *(const f16x8*)(ka_);       S##K1 = *(const f16x8*)(ka_ + 16); \
    S##K2 = *(const f16x8*)(ka_ + 32);  S##K3 = *(const f16x8*)(ka_ + 48); \
    const f16_t* qa_ = qbase + (size_t)(J) * 64; \
    S##Q0 = *(const f16x8*)(qa_);       S##Q1 = *(const f16x8*)(qa_ + 16); \
    S##Q2 = *(const f16x8*)(qa_ + 32);  S##Q3 = *(const f16x8*)(qa_ + 48); \
    const f16_t* va_ = vbase + (J); \
    S##V00 = *(const f16x8*)(va_);          S##V01 = *(const f16x8*)(va_ + 16); \
    S##V10 = *(const f16x8*)(va_ + 32 * NN); S##V11 = *(const f16x8*)(va_ + 32 * NN + 16); \
} while (0)

#define COMPUTE(S) do { \
    f32x16 sc = {}; \
    sc = __builtin_amdgcn_mfma_f32_32x32x16_f16(S##K0, Bq0, sc, 0, 0, 0); \
    sc = __builtin_amdgcn_mfma_f32_32x32x16_f16(S##K1, Bq1, sc, 0, 0, 0); \
    sc = __builtin_amdgcn_mfma_f32_32x32x16_f16(S##K2, Bq2, sc, 0, 0, 0); \
    sc = __builtin_amdgcn_mfma_f32_32x32x16_f16(S##K3, Bq3, sc, 0, 0, 0); \
    sc = __builtin_amdgcn_mfma_f32_32x32x16_f16(S##Q0, Bq4, sc, 0, 0, 0); \
    sc = __builtin_amdgcn_mfma_f32_32x32x16_f16(S##Q1, Bq5, sc, 0, 0, 0); \
    sc = __builtin_amdgcn_mfma_f32_32x32x16_f16(S##Q2, Bq6, sc, 0, 0, 0); \
    sc = __builtin_amdgcn_mfma_f32_32x32x16_f16(S##Q3, Bq7, sc, 0, 0, 0); \
    float mt = sc[0]; \
    _Pragma("unroll") \
    for (int r = 1; r < 16; ++r) mt = fmaxf(mt, sc[r]); \
    mt = fmaxf(mt, __shfl_xor(mt, 32, 64)); \
    if (!__all(mt <= m_run + 8.0f)) { \
        float mnew = fmaxf(m_run, mt); \
        float alpha = __expf(m_run - mnew); \
        m_run = mnew; l_run *= alpha; \
        _Pragma("unroll") \
        for (int r = 0; r < 16; ++r) { accD0[r] *= alpha; accD1[r] *= alpha; } \
    } \
    float p[16]; float rs = 0.0f; \
    _Pragma("unroll") \
    for (int r = 0; r < 16; ++r) { p[r] = __expf(sc[r] - m_run); rs += p[r]; } \
    rs += __shfl_xor(rs, 32, 64); \
    l_run += rs; \
    int w0 = __builtin_bit_cast(int, __builtin_amdgcn_cvt_pkrtz(p[0], p[1])); \
    int w1 = __builtin_bit_cast(int, __builtin_amdgcn_cvt_pkrtz(p[2], p[3])); \
    int w2 = __builtin_bit_cast(int, __builtin_amdgcn_cvt_pkrtz(p[4], p[5])); \
    int w3 = __builtin_bit_cast(int, __builtin_amdgcn_cvt_pkrtz(p[6], p[7])); \
    int w4 = __builtin_bit_cast(int, __builtin_amdgcn_cvt_pkrtz(p[8], p[9])); \
    int w5 = __builtin_bit_cast(int, __builtin_amdgcn_cvt_pkrtz(p[10], p[11])); \
    int w6 = __builtin_bit_cast(int, __builtin_amdgcn_cvt_pkrtz(p[12], p[13])); \
    int w7 = __builtin_bit_cast(int, __builtin_amdgcn_cvt_pkrtz(p[14], p[15])); \
    int x0 = __shfl_xor(w0, 32, 64), x1 = __shfl_xor(w1, 32, 64); \
    int x2 = __shfl_xor(w2, 32, 64), x3 = __shfl_xor(w3, 32, 64); \
    int x4 = __shfl_xor(w4, 32, 64), x5 = __shfl_xor(w5, 32, 64); \
    int x6 = __shfl_xor(w6, 32, 64), x7 = __shfl_xor(w7, 32, 64); \
    i32x4 pb0 = { half ? x2 : w0, half ? x3 : w1, half ? w2 : x0, half ? w3 : x1 }; \
    i32x4 pb1 = { half ? x6 : w4, half ? x7 : w5, half ? w6 : x4, half ? w7 : x5 }; \
    f16x8 Pf0 = __builtin_bit_cast(f16x8, pb0); \
    f16x8 Pf1 = __builtin_bit_cast(f16x8, pb1); \
    accD0 = __builtin_amdgcn_mfma_f32_32x32x16_f16(S##V00, Pf0, accD0, 0, 0, 0); \
    accD0 = __builtin_amdgcn_mfma_f32_32x32x16_f16(S##V01, Pf1, accD0, 0, 0, 0); \
    accD1 = __builtin_amdgcn_mfma_f32_32x32x16_f16(S##V10, Pf0, accD1, 0, 0, 0); \
    accD1 = __builtin_amdgcn_mfma_f32_32x32x16_f16(S##V11, Pf1, accD1, 0, 0, 0); \
} while (0)

    LOADT(a, 0);
    for (int t = 0; t < 32; t += 2) {
        LOADT(b, (t + 1) * 32);
        COMPUTE(a);
        LOADT(a, (size_t)(((t + 2) & 31) * 32));
        COMPUTE(b);
    }
#undef LOADT
#undef COMPUTE

    float inv = 1.0f / l_run;
    size_t orow = ((size_t)b * NN + q0 + lq) * 256 + h * 64;
    #pragma unroll
    for (int rg = 0; rg < 4; ++rg) {
        f16x4 s0, s1;
        #pragma unroll
        for (int c = 0; c < 4; ++c) {
            s0[c] = (f16_t)(accD0[rg * 4 + c] * inv);
            s1[c] = (f16_t)(accD1[rg * 4 + c] * inv);
        }
        *(f16x4*)&o[orow + rg * 8 + half * 4] = s0;
        *(f16x4*)&o[orow + 32 + rg * 8 + half * 4] = s1;
    }
}

// LayerNorm over P=256: o [B][N][256] f16 -> yt f16. One wave per row.
__global__ __launch_bounds__(256) void ln_k(const f16_t* __restrict__ o,
                                            f16_t* __restrict__ yt,
                                            const float* __restrict__ lw,
                                            const float* __restrict__ lb)
{
    int tid = threadIdx.x;
    int wv = tid >> 6, l = tid & 63;
    size_t row = (size_t)blockIdx.x * 4 + wv;
    f16x4 v4 = ((const f16x4*)(o + row * 256))[l];
    float v[4];
    #pragma unroll
    for (int j = 0; j < 4; ++j) v[j] = (float)v4[j];
    float s = v[0] + v[1] + v[2] + v[3];
    float q = v[0]*v[0] + v[1]*v[1] + v[2]*v[2] + v[3]*v[3];
    #pragma unroll
    for (int off = 1; off < 64; off <<= 1) {
        s += __shfl_xor(s, off, 64);
        q += __shfl_xor(q, off, 64);
    }
    float mean = s * (1.0f / 256.0f);
    float var = q * (1.0f / 256.0f) - mean * mean;
    float rstd = rsqrtf(var + 1e-6f);
    f32x4 w4 = ((const f32x4*)lw)[l];
    f32x4 b4 = ((const f32x4*)lb)[l];
    f16x4 o4;
    #pragma unroll
    for (int j = 0; j < 4; ++j)
        o4[j] = (f16_t)((v[j] - mean) * rstd * w4[j] + b4[j]);
    ((f16x4*)(yt + row * 256))[l] = o4;
}

extern "C" void kernel_launch(void* const* d_in, const int* in_sizes, int n_in,
                              void* d_out, int out_size, void* d_ws, size_t ws_size,
                              hipStream_t stream) {
    const float* x     = (const float*)d_in[0];
    const float* w_ds  = (const float*)d_in[1];
    const float* wq    = (const float*)d_in[2];
    const float* bq    = (const float*)d_in[3];
    const float* wk    = (const float*)d_in[4];
    const float* bk    = (const float*)d_in[5];
    const float* wv    = (const float*)d_in[6];
    const float* bv    = (const float*)d_in[7];
    const float* rel_h = (const float*)d_in[8];
    const float* rel_w = (const float*)d_in[9];
    const float* ln_w  = (const float*)d_in[10];
    const float* ln_b  = (const float*)d_in[11];
    const float* w1    = (const float*)d_in[12];
    float* out = (float*)d_out;

    f16_t* xt    = (f16_t*)d_ws;             // [B][N][C]       32 MB
    f16_t* wdsh  = xt + 16777216;            // [256][1024]
    f16_t* wqkv  = wdsh + 262144;            // [768][256]
    f16_t* w1h   = wqkv + 196608;            // [1024][256]
    f16_t* post  = w1h + 262144;             // [4][1024][64]
    f16_t* out0t = post + 262144;            // [B][N][256]
    f16_t* qt    = out0t + 4194304;          // [B*4][N][64]
    f16_t* kt    = qt + 4194304;
    f16_t* vb    = kt + 4194304;             // [B*4][64][N]
    f16_t* ytb   = vb + 4194304;             // [B][N][256]
    f16_t* oat   = ytb + 4194304;            // [B][N][256]
    float* bqkv  = (float*)(oat + 4194304);  // [768]

    prep_k<<<961, 256, 0, stream>>>(w_ds, wq, wk, wv, w1, rel_h, rel_w,
                                    bq, bk, bv, wdsh, wqkv, w1h, post, bqkv);
    transpose_xk<<<dim3(16, 16, 16), 256, 0, stream>>>(x, xt);

    // out0_t[b][n][p] = w_ds * x
    hgemm<<<dim3(32, 4, 16), 64, 0, stream>>>(wdsh, xt, nullptr, nullptr,
                                              out0t, nullptr, nullptr, nullptr,
                                              PP, NN, INC, 0);
    // q,k,v in one launch (M=768)
    hgemm<<<dim3(32, 12, 16), 64, 0, stream>>>(wqkv, out0t, bqkv, nullptr,
                                               qt, kt, vb, nullptr,
                                               768, NN, PP, 1);
    // attention -> oat [b][n][256] f16
    attn_mfma<<<dim3(32, 4, 16), 64, 0, stream>>>(qt, kt, vb, post, oat);
    // layernorm -> ytb f16
    ln_k<<<4096, 256, 0, stream>>>(oat, ytb, ln_w, ln_b);
    // out = gelu(w1 * y) + x
    hgemm<<<dim3(32, 16, 16), 64, 0, stream>>>(w1h, ytb, nullptr, x,
                                               nullptr, nullptr, nullptr, out,
                                               INC, NN, PP, 3);
}